// Round 2
// baseline (1303.831 us; speedup 1.0000x reference)
//
#include <hip/hip_runtime.h>
#include <stdint.h>

#define OUTF 11008
#define INF  4096
#define NG   32      // groups = INF/128
#define TOK  8192
#define KB4  2048    // int32 per qweight row = INF/2

// ---- main GEMM geometry: 256x256 tile, 8 waves, fine 8-phase counted-vmcnt ----
#define BM 256
#define BN 256
#define BK 64
#define NT (INF / BK)    // 64 K-tiles
#define GX (OUTF / BN)   // 43
#define GY (TOK / BM)    // 32
#define NWG (GX * GY)    // 1376, % 8 == 0 -> simple bijective XCD swizzle

typedef unsigned short u16;
typedef __attribute__((ext_vector_type(8))) short bf16x8;
typedef __attribute__((ext_vector_type(4))) float f32x4;

// fp32 -> bf16 round-to-nearest-even (inputs finite)
__device__ inline u16 f2bf(float f) {
  union { float f; uint32_t u; } v; v.f = f;
  return (u16)((v.u + 0x7fff + ((v.u >> 16) & 1)) >> 16);
}

// async global->LDS, 16B per lane; lds dest must be wave-uniform base (+lane*16 implicit)
__device__ inline void async_copy16(const void* g, const void* l) {
  __builtin_amdgcn_global_load_lds(
      (__attribute__((address_space(1))) void*)(g),
      (__attribute__((address_space(3))) void*)(l), 16, 0, 0);
}

#define FENCE() asm volatile("" ::: "memory")
#define BAR()   do { FENCE(); __builtin_amdgcn_s_barrier(); FENCE(); } while (0)
#define VMCNT(n) asm volatile("s_waitcnt vmcnt(" #n ")" ::: "memory")
#define LGKM0()  asm volatile("s_waitcnt lgkmcnt(0)" ::: "memory")

// ---------------- preprocessing kernels (unchanged) ----------------

__global__ void dequant_w(const int* __restrict__ QW, const float* __restrict__ scales,
                          const float* __restrict__ zeros, u16* __restrict__ Wb) {
  const int idx = blockIdx.x * 256 + threadIdx.x;   // one per 8 packed ints
  const int e = idx * 8;
  const int o = e >> 11;            // /KB4
  const int c = e & (KB4 - 1);      // multiple of 8 -> both int4s in same group
  const int g = c >> 6;
  const float s = scales[o * NG + g];
  const float z = zeros[o * NG + g];
  const float zs = -z * s;
#pragma unroll
  for (int h = 0; h < 2; ++h) {
    const int4 q = *(const int4*)(QW + (size_t)o * KB4 + c + h * 4);
    const int qq[4] = {q.x, q.y, q.z, q.w};
    union { u16 t[8]; int4 v; } u;
#pragma unroll
    for (int j = 0; j < 4; ++j) {
      u.t[2 * j]     = f2bf(fmaf((float)(qq[j] & 15), s, zs));
      u.t[2 * j + 1] = f2bf(fmaf((float)((qq[j] >> 4) & 15), s, zs));
    }
    *(int4*)(Wb + (size_t)o * INF + 2 * (c + h * 4)) = u.v;
  }
}

__global__ void cvt_x(const float* __restrict__ X, u16* __restrict__ Xb) {
  const size_t base = ((size_t)blockIdx.x * 256 + threadIdx.x) * 16;
#pragma unroll
  for (int h = 0; h < 2; ++h) {
    const float4 a = *(const float4*)(X + base + h * 8);
    const float4 b = *(const float4*)(X + base + h * 8 + 4);
    union { u16 t[8]; int4 v; } u;
    u.t[0] = f2bf(a.x); u.t[1] = f2bf(a.y); u.t[2] = f2bf(a.z); u.t[3] = f2bf(a.w);
    u.t[4] = f2bf(b.x); u.t[5] = f2bf(b.y); u.t[6] = f2bf(b.z); u.t[7] = f2bf(b.w);
    *(int4*)(Xb + base + h * 8) = u.v;
  }
}

// ---------------- main GEMM: 256^2 tile, fine-interleaved 8-phase ----------------
// LDS XOR-swizzle: 16B granule g of local row r at g ^ (r&7), via pre-swizzled
// GLOBAL source granule + linear LDS dest (global_load_lds requirement).
// A-frag: A[m=lane&15][k=(lane>>4)*8+j]; C/D: col=lane&15, row=(lane>>4)*4+reg.
//
// Phase split per K-tile T (slot S = T&1): phase = (ks, m-half). Each phase:
//   { ds_reads (8 or 4) + staged global_load_lds | BAR | lgkm0 | 16 MFMA | BAR }
// ds_read spread 8/4/8/4 (was 12/12/0/0) -- the m196 fine-interleave lever.
//
// Region liveness (slot S, per 64-row group; reads retire collectively at the
// post-MFMA barrier of the phase that issued them):
//   A rows {0-63,128-191}  read ph0,ph2 -> stage T+2 copy at ph3
//   A rows {64-127,192-255} read ph1,ph3 -> stage T+2 copy at (T+1) ph0
//   B all rows              read ph0,ph2 -> stage T+2 copy at ph3
// vmcnt: 8 loads/tile (2 @ph0 for T+1, 6 @ph3 for T+2). At T ph3 after issue:
// outstanding <= T+1's 8 + T+2's 6 = 14; VMCNT(6) drains all of T+1 while
// leaving T+2's 6 in flight (never 0 in the main loop); BAR makes it collective.

__global__ __launch_bounds__(512, 2) void gemm_pre512(const u16* __restrict__ A,
                                                      const u16* __restrict__ B,
                                                      const float* __restrict__ bias,
                                                      float* __restrict__ C) {
  __shared__ __align__(16) u16 As[2][BM * BK];   // 2 x 32 KB
  __shared__ __align__(16) u16 Bs[2][BN * BK];   // 2 x 32 KB  (total 128 KB)
  const int tid = threadIdx.x;
  const int lane = tid & 63;
  const int wid = __builtin_amdgcn_readfirstlane(tid >> 6);

  // XCD-aware bijective block swizzle (NWG % 8 == 0)
  const int lin = blockIdx.x;
  const int wg = (lin & 7) * (NWG / 8) + (lin >> 3);
  const int bm = wg / GX;
  const int bn = wg % GX;

  const u16* Ab = A + (size_t)bm * BM * INF;
  const u16* Bb = B + (size_t)bn * BN * INF;

  // staging addressing: one global_load_lds (all 8 waves) covers 64 rows
  const int rowoff = tid >> 3;                    // 0..63
  const int gran = (tid & 7) ^ (rowoff & 7);      // pre-swizzled source granule
  const u16* Asrc = Ab + (size_t)rowoff * INF + gran * 8;
  const u16* Bsrc = Bb + (size_t)rowoff * INF + gran * 8;
  const int wid8 = wid * 8;

  // frag addressing
  const int rr = lane & 15;
  const int q4 = lane >> 4;
  const int wm = wid >> 2;   // 0..1 -> 128-row half of A tile
  const int wn = wid & 3;    // 0..3 -> 64-row quarter of B tile

  f32x4 acc[8][4] = {};
  bf16x8 af[4];              // per-phase A frags (one ks, one m-half)
  bf16x8 bfv[4];             // per-ks B frags (live across the two MH phases)

// single 64-row staging call (1 VMEM instr/wave; wave w covers rows R0+8w..+7)
#define STAGE1(LDS, SRC, TT, R0)                                               \
  async_copy16((SRC) + (size_t)(R0) * INF + (size_t)(TT) * BK,                 \
               (const char*)(LDS) + ((R0) + wid8) * 128);

#define PH_READ_A(S, KS, MH)                                                   \
  _Pragma("unroll") for (int mi = 0; mi < 4; ++mi)                             \
    af[mi] = *(const bf16x8*)&As[S][(wm * 128 + ((MH) * 4 + mi) * 16 + rr) *   \
                                        BK +                                   \
                                    ((((KS) * 4 + q4) ^ (rr & 7)) * 8)];

#define PH_READ_B(S, KS)                                                       \
  _Pragma("unroll") for (int ni = 0; ni < 4; ++ni)                             \
    bfv[ni] = *(const bf16x8*)&Bs[S][(wn * 64 + ni * 16 + rr) * BK +           \
                                     ((((KS) * 4 + q4) ^ (rr & 7)) * 8)];

#define PH_MFMA(MH)                                                            \
  do {                                                                         \
    __builtin_amdgcn_s_setprio(1);                                             \
    _Pragma("unroll") for (int mi = 0; mi < 4; ++mi)                           \
      _Pragma("unroll") for (int ni = 0; ni < 4; ++ni)                         \
        acc[(MH) * 4 + mi][ni] = __builtin_amdgcn_mfma_f32_16x16x32_bf16(      \
            af[mi], bfv[ni], acc[(MH) * 4 + mi][ni], 0, 0, 0);                 \
    __builtin_amdgcn_s_setprio(0);                                             \
  } while (0)

#define TILE(S, T)                                                             \
  do {                                                                         \
    /* ph0: ks0, MH0 */                                                        \
    PH_READ_A(S, 0, 0); PH_READ_B(S, 0);                                       \
    if ((T) + 1 < NT) {                                                        \
      STAGE1(&As[(S) ^ 1][0], Asrc, (T) + 1, 64)                               \
      STAGE1(&As[(S) ^ 1][0], Asrc, (T) + 1, 192)                              \
    }                                                                          \
    BAR(); LGKM0(); PH_MFMA(0); BAR();                                         \
    /* ph1: ks0, MH1 */                                                        \
    PH_READ_A(S, 0, 1);                                                        \
    BAR(); LGKM0(); PH_MFMA(1); BAR();                                         \
    /* ph2: ks1, MH0 */                                                        \
    PH_READ_A(S, 1, 0); PH_READ_B(S, 1);                                       \
    BAR(); LGKM0(); PH_MFMA(0); BAR();                                         \
    /* ph3: ks1, MH1 */                                                        \
    PH_READ_A(S, 1, 1);                                                        \
    if ((T) + 2 < NT) {                                                        \
      STAGE1(&As[S][0], Asrc, (T) + 2, 0)                                      \
      STAGE1(&As[S][0], Asrc, (T) + 2, 128)                                    \
      STAGE1(&Bs[S][0], Bsrc, (T) + 2, 0)                                      \
      STAGE1(&Bs[S][0], Bsrc, (T) + 2, 64)                                     \
      STAGE1(&Bs[S][0], Bsrc, (T) + 2, 128)                                    \
      STAGE1(&Bs[S][0], Bsrc, (T) + 2, 192)                                    \
      VMCNT(6);                                                                \
    } else {                                                                   \
      VMCNT(0);                                                                \
    }                                                                          \
    BAR(); LGKM0(); PH_MFMA(1); BAR();                                         \
  } while (0)

  // prologue: T0 full (8 loads) -> slot0; T1 minus A{64-127,192-255} (6) -> slot1
  STAGE1(&As[0][0], Asrc, 0, 0)   STAGE1(&As[0][0], Asrc, 0, 64)
  STAGE1(&As[0][0], Asrc, 0, 128) STAGE1(&As[0][0], Asrc, 0, 192)
  STAGE1(&Bs[0][0], Bsrc, 0, 0)   STAGE1(&Bs[0][0], Bsrc, 0, 64)
  STAGE1(&Bs[0][0], Bsrc, 0, 128) STAGE1(&Bs[0][0], Bsrc, 0, 192)
  STAGE1(&As[1][0], Asrc, 1, 0)   STAGE1(&As[1][0], Asrc, 1, 128)
  STAGE1(&Bs[1][0], Bsrc, 1, 0)   STAGE1(&Bs[1][0], Bsrc, 1, 64)
  STAGE1(&Bs[1][0], Bsrc, 1, 128) STAGE1(&Bs[1][0], Bsrc, 1, 192)
  VMCNT(6);   // 14 outstanding -> oldest 8 (all of T0) drained
  BAR();

  for (int t = 0; t < NT; t += 2) {
    TILE(0, t);
    TILE(1, t + 1);
  }

  // epilogue
  const int ncol = lane & 15;
  const int qrow = (lane >> 4) * 4;
  float bv[4];
#pragma unroll
  for (int ni = 0; ni < 4; ++ni)
    bv[ni] = bias[bn * BN + wn * 64 + ni * 16 + ncol];
#pragma unroll
  for (int mi = 0; mi < 8; ++mi)
#pragma unroll
    for (int ni = 0; ni < 4; ++ni) {
      const int gn = bn * BN + wn * 64 + ni * 16 + ncol;
#pragma unroll
      for (int r = 0; r < 4; ++r) {
        const int gm = bm * BM + wm * 128 + mi * 16 + qrow + r;
        C[(size_t)gm * OUTF + gn] = acc[mi][ni][r] + bv[ni];
      }
    }
}

// ---------------- fused fallback (no workspace requirement) ----------------

#define FBM 128
#define FBN 128

#define FMFMA_COMPUTE()                                                       \
  do {                                                                        \
    const int frr = lane & 15;                                                \
    const int fq4 = lane >> 4;                                                \
    _Pragma("unroll") for (int ks = 0; ks < 2; ++ks) {                        \
      bf16x8 fa[4], fb[4];                                                    \
      const int kk = (((ks * 4 + fq4) ^ (frr & 7)) * 8);                      \
      _Pragma("unroll") for (int i = 0; i < 4; ++i) {                         \
        fa[i] = *(const bf16x8*)&Asf[(mwave + i * 16 + frr) * BK + kk];       \
        fb[i] = *(const bf16x8*)&Bsf[(nwave + i * 16 + frr) * BK + kk];       \
      }                                                                       \
      _Pragma("unroll") for (int mi = 0; mi < 4; ++mi)                        \
        _Pragma("unroll") for (int ni = 0; ni < 4; ++ni)                      \
          facc[mi][ni] = __builtin_amdgcn_mfma_f32_16x16x32_bf16(             \
              fa[mi], fb[ni], facc[mi][ni], 0, 0, 0);                         \
    }                                                                         \
  } while (0)

__global__ __launch_bounds__(256) void gemm_fused(const float* __restrict__ X,
                                                  const int* __restrict__ QW,
                                                  const float* __restrict__ scales,
                                                  const float* __restrict__ zeros,
                                                  const float* __restrict__ bias,
                                                  float* __restrict__ C) {
  __shared__ __align__(16) u16 Asf[FBM * BK];
  __shared__ __align__(16) u16 Bsf[FBN * BK];
  const int tid = threadIdx.x;
  const int lane = tid & 63;
  const int wid = tid >> 6;
  const int bm = blockIdx.y, bn = blockIdx.x;
  const int row = tid >> 1;
  const int half = tid & 1;
  const float* xr = X + (size_t)(bm * FBM + row) * INF + half * 32;
  const int* qr = QW + (size_t)(bn * FBN + row) * KB4 + half * 16;
  const float* srow = scales + (size_t)(bn * FBN + row) * NG;
  const float* zrow = zeros + (size_t)(bn * FBN + row) * NG;
  const int mwave = (wid >> 1) * 64;
  const int nwave = (wid & 1) * 64;
  f32x4 facc[4][4] = {};

  for (int kb = 0; kb < INF / BK; ++kb) {
    const int k0 = kb * BK;
    union { u16 t[32]; int4 v[4]; } ta, tb;
#pragma unroll
    for (int j = 0; j < 8; ++j) {
      const float4 f = *(const float4*)(xr + k0 + j * 4);
      ta.t[4 * j]     = f2bf(f.x);
      ta.t[4 * j + 1] = f2bf(f.y);
      ta.t[4 * j + 2] = f2bf(f.z);
      ta.t[4 * j + 3] = f2bf(f.w);
    }
    {
      const float s = srow[kb >> 1];
      const float zs = -zrow[kb >> 1] * s;
#pragma unroll
      for (int j = 0; j < 4; ++j) {
        const int4 q = *(const int4*)(qr + kb * 32 + j * 4);
        const int qq[4] = {q.x, q.y, q.z, q.w};
#pragma unroll
        for (int u = 0; u < 4; ++u) {
          tb.t[8 * j + 2 * u]     = f2bf(fmaf((float)(qq[u] & 15), s, zs));
          tb.t[8 * j + 2 * u + 1] = f2bf(fmaf((float)((qq[u] >> 4) & 15), s, zs));
        }
      }
    }
    __syncthreads();
#pragma unroll
    for (int j = 0; j < 4; ++j) {
      *(int4*)&Asf[row * BK + (((half * 4 + j) ^ (row & 7)) * 8)] = ta.v[j];
      *(int4*)&Bsf[row * BK + (((half * 4 + j) ^ (row & 7)) * 8)] = tb.v[j];
    }
    __syncthreads();
    FMFMA_COMPUTE();
  }
  {
    const int ncol = lane & 15;
    const int qrow = (lane >> 4) * 4;
#pragma unroll
    for (int mi = 0; mi < 4; ++mi)
#pragma unroll
      for (int ni = 0; ni < 4; ++ni) {
        const int gn = bn * FBN + nwave + ni * 16 + ncol;
        const float bvv = bias[gn];
#pragma unroll
        for (int r = 0; r < 4; ++r) {
          const int gm = bm * FBM + mwave + mi * 16 + qrow + r;
          C[(size_t)gm * OUTF + gn] = facc[mi][ni][r] + bvv;
        }
      }
  }
}

// ---------------- launch ----------------

extern "C" void kernel_launch(void* const* d_in, const int* in_sizes, int n_in,
                              void* d_out, int out_size, void* d_ws, size_t ws_size,
                              hipStream_t stream) {
  const float* x = (const float*)d_in[0];
  const int* qw = (const int*)d_in[1];
  const float* scales = (const float*)d_in[2];
  const float* zeros = (const float*)d_in[3];
  const float* bias = (const float*)d_in[4];
  float* out = (float*)d_out;

  const size_t needW = (size_t)OUTF * INF * sizeof(u16);  // 90,177,536 B
  const size_t needX = (size_t)TOK * INF * sizeof(u16);   // 67,108,864 B

  if (ws_size >= needW + needX) {
    u16* Wb = (u16*)d_ws;
    u16* Xb = (u16*)((char*)d_ws + needW);
    dequant_w<<<(OUTF * KB4 / 8) / 256, 256, 0, stream>>>(qw, scales, zeros, Wb);
    cvt_x<<<(TOK * INF / 16) / 256, 256, 0, stream>>>(x, Xb);
    gemm_pre512<<<dim3(NWG), 512, 0, stream>>>(Xb, Wb, bias, out);
  } else {
    gemm_fused<<<dim3(OUTF / FBN, FBM ? TOK / FBM : 1), 256, 0, stream>>>(x, qw, scales, zeros, bias, out);
  }
}

// Round 3
// 1274.947 us; speedup vs baseline: 1.0227x; 1.0227x over previous
//
#include <hip/hip_runtime.h>
#include <stdint.h>

#define OUTF 11008
#define INF  4096
#define NG   32      // groups = INF/128
#define TOK  8192
#define KB4  2048    // int32 per qweight row = INF/2

// ---- main GEMM geometry: 256x256 tile, 8 waves, 2-barrier/tile counted-vmcnt ----
#define BM 256
#define BN 256
#define BK 64
#define NT (INF / BK)    // 64 K-tiles
#define GX (OUTF / BN)   // 43
#define GY (TOK / BM)    // 32
#define NWG (GX * GY)    // 1376, % 8 == 0 -> simple bijective XCD swizzle

typedef unsigned short u16;
typedef __attribute__((ext_vector_type(8))) short bf16x8;
typedef __attribute__((ext_vector_type(4))) float f32x4;

// fp32 -> bf16 round-to-nearest-even (inputs finite)
__device__ inline u16 f2bf(float f) {
  union { float f; uint32_t u; } v; v.f = f;
  return (u16)((v.u + 0x7fff + ((v.u >> 16) & 1)) >> 16);
}

// async global->LDS, 16B per lane; lds dest must be wave-uniform base (+lane*16 implicit)
__device__ inline void async_copy16(const void* g, const void* l) {
  __builtin_amdgcn_global_load_lds(
      (__attribute__((address_space(1))) void*)(g),
      (__attribute__((address_space(3))) void*)(l), 16, 0, 0);
}

#define FENCE() asm volatile("" ::: "memory")
#define BAR()   do { FENCE(); __builtin_amdgcn_s_barrier(); FENCE(); } while (0)
#define VMCNT(n) asm volatile("s_waitcnt vmcnt(" #n ")" ::: "memory")

// ---------------- fused preprocessing kernel ----------------
// One grid-stride kernel, fully coalesced units:
//   X-units  (i < NXU): 4 consecutive f32 (16B load) -> 4 bf16 (8B store)
//   W-units  (i >= NXU): 4 consecutive packed int32 (16B load) -> 8 bf16 (16B store)
// All loads/stores lane-contiguous. Total traffic ~381 MB -> ~60 us at BW limit.

#define NXU ((long long)TOK * INF / 4)    // 8,388,608
#define NWU ((long long)OUTF * KB4 / 4)   // 5,636,096
#define PREPBLK 2048

__global__ __launch_bounds__(256) void prep(const float* __restrict__ X,
                                            const int* __restrict__ QW,
                                            const float* __restrict__ scales,
                                            const float* __restrict__ zeros,
                                            u16* __restrict__ Xb,
                                            u16* __restrict__ Wb) {
  const long long stride = (long long)gridDim.x * 256;
  for (long long i = (long long)blockIdx.x * 256 + threadIdx.x; i < NXU + NWU;
       i += stride) {
    if (i < NXU) {
      const float4 f = ((const float4*)X)[i];
      union { u16 t[4]; uint2 v; } u;
      u.t[0] = f2bf(f.x); u.t[1] = f2bf(f.y);
      u.t[2] = f2bf(f.z); u.t[3] = f2bf(f.w);
      ((uint2*)Xb)[i] = u.v;
    } else {
      const long long j = i - NXU;          // w-unit: 4 ints of row o
      const int o = (int)(j >> 9);          // 512 units per row (2048/4)
      const int c0 = ((int)j & 511) * 4;    // int column; group = c0/64 (4 | 64)
      const int g = c0 >> 6;
      const float s = scales[o * NG + g];
      const float zs = -zeros[o * NG + g] * s;
      const int4 q = ((const int4*)QW)[j];
      const int qq[4] = {q.x, q.y, q.z, q.w};
      union { u16 t[8]; int4 v; } u;
#pragma unroll
      for (int k = 0; k < 4; ++k) {
        u.t[2 * k]     = f2bf(fmaf((float)(qq[k] & 15), s, zs));
        u.t[2 * k + 1] = f2bf(fmaf((float)((qq[k] >> 4) & 15), s, zs));
      }
      ((int4*)Wb)[j] = u.v;                 // bf16 cols [2*c0, 2*c0+8)
    }
  }
}

// ---------------- main GEMM: 256^2 tile, 2 barriers/tile ----------------
// LDS XOR-swizzle: 16B granule g of local row r at g ^ (r&7), via pre-swizzled
// GLOBAL source granule + linear LDS dest (global_load_lds requirement).
// A-frag: A[m=lane&15][k=(lane>>4)*8+j]; C/D: col=lane&15, row=(lane>>4)*4+reg.
//
// Schedule per K-tile T (slot S = T&1):
//   4 read/MFMA sub-phases, NO intra-tile barriers, NO explicit lgkm drains:
//   slot S is read-only for the whole tile, so waves may skew freely; the
//   compiler's fine-grained lgkmcnt(N) lets MFMAs overlap the LDS drain, and
//   skewed waves fill each other's pipe gaps (setprio arbitrates for MFMA).
//   BAR#1: all waves done reading slot S  -> safe to re-stage slot S (T+2)
//   VMCNT(8): counted - drains T+1's 8 loads (issued last tile), leaves T+2's
//             8 in flight (never 0 in main loop)
//   BAR#2: makes T+1's staged data collectively visible before its reads.
// Skew bound: a wave cannot stage slot S^1 (at tile T+1's BAR#1) before all
// waves finished reading it (they must reach that same barrier). Safe.

__global__ __launch_bounds__(512, 2) void gemm_pre512(const u16* __restrict__ A,
                                                      const u16* __restrict__ B,
                                                      const float* __restrict__ bias,
                                                      float* __restrict__ C) {
  __shared__ __align__(16) u16 As[2][BM * BK];   // 2 x 32 KB
  __shared__ __align__(16) u16 Bs[2][BN * BK];   // 2 x 32 KB  (total 128 KB)
  const int tid = threadIdx.x;
  const int lane = tid & 63;
  const int wid = __builtin_amdgcn_readfirstlane(tid >> 6);

  // XCD-aware bijective block swizzle (NWG % 8 == 0)
  const int lin = blockIdx.x;
  const int wg = (lin & 7) * (NWG / 8) + (lin >> 3);
  const int bm = wg / GX;
  const int bn = wg % GX;

  const u16* Ab = A + (size_t)bm * BM * INF;
  const u16* Bb = B + (size_t)bn * BN * INF;

  // staging addressing: one global_load_lds (all 8 waves) covers 64 rows
  const int rowoff = tid >> 3;                    // 0..63
  const int gran = (tid & 7) ^ (rowoff & 7);      // pre-swizzled source granule
  const u16* Asrc = Ab + (size_t)rowoff * INF + gran * 8;
  const u16* Bsrc = Bb + (size_t)rowoff * INF + gran * 8;
  const int wid8 = wid * 8;

  // frag addressing
  const int rr = lane & 15;
  const int q4 = lane >> 4;
  const int wm = wid >> 2;   // 0..1 -> 128-row half of A tile
  const int wn = wid & 3;    // 0..3 -> 64-row quarter of B tile

  f32x4 acc[8][4] = {};
  bf16x8 af[4];              // per-sub-phase A frags (one ks, one m-half)
  bf16x8 bfv[4];             // per-ks B frags (live across the two MH phases)

// single 64-row staging call (1 VMEM instr/wave; wave w covers rows R0+8w..+7)
#define STAGE1(LDS, SRC, TT, R0)                                               \
  async_copy16((SRC) + (size_t)(R0) * INF + (size_t)(TT) * BK,                 \
               (const char*)(LDS) + ((R0) + wid8) * 128);

#define STAGE_ALL(S, TT)                                                       \
  do {                                                                         \
    STAGE1(&As[S][0], Asrc, TT, 0)   STAGE1(&As[S][0], Asrc, TT, 64)           \
    STAGE1(&As[S][0], Asrc, TT, 128) STAGE1(&As[S][0], Asrc, TT, 192)          \
    STAGE1(&Bs[S][0], Bsrc, TT, 0)   STAGE1(&Bs[S][0], Bsrc, TT, 64)           \
    STAGE1(&Bs[S][0], Bsrc, TT, 128) STAGE1(&Bs[S][0], Bsrc, TT, 192)          \
  } while (0)

#define PH_READ_A(S, KS, MH)                                                   \
  _Pragma("unroll") for (int mi = 0; mi < 4; ++mi)                             \
    af[mi] = *(const bf16x8*)&As[S][(wm * 128 + ((MH) * 4 + mi) * 16 + rr) *   \
                                        BK +                                   \
                                    ((((KS) * 4 + q4) ^ (rr & 7)) * 8)];

#define PH_READ_B(S, KS)                                                       \
  _Pragma("unroll") for (int ni = 0; ni < 4; ++ni)                             \
    bfv[ni] = *(const bf16x8*)&Bs[S][(wn * 64 + ni * 16 + rr) * BK +           \
                                     ((((KS) * 4 + q4) ^ (rr & 7)) * 8)];

#define PH_MFMA(MH)                                                            \
  do {                                                                         \
    __builtin_amdgcn_s_setprio(1);                                             \
    _Pragma("unroll") for (int mi = 0; mi < 4; ++mi)                           \
      _Pragma("unroll") for (int ni = 0; ni < 4; ++ni)                         \
        acc[(MH) * 4 + mi][ni] = __builtin_amdgcn_mfma_f32_16x16x32_bf16(      \
            af[mi], bfv[ni], acc[(MH) * 4 + mi][ni], 0, 0, 0);                 \
    __builtin_amdgcn_s_setprio(0);                                             \
  } while (0)

#define TILE(S, T)                                                             \
  do {                                                                         \
    PH_READ_A(S, 0, 0); PH_READ_B(S, 0); PH_MFMA(0);                           \
    PH_READ_A(S, 0, 1); PH_MFMA(1);                                            \
    PH_READ_A(S, 1, 0); PH_READ_B(S, 1); PH_MFMA(0);                           \
    PH_READ_A(S, 1, 1); PH_MFMA(1);                                            \
    BAR(); /* all waves done reading slot S */                                 \
    if ((T) + 2 < NT) { STAGE_ALL(S, (T) + 2); VMCNT(8); } else { VMCNT(0); }  \
    BAR(); /* T+1's staged data collectively visible */                        \
  } while (0)

  // prologue: stage T0 -> slot0 (8 loads), T1 -> slot1 (8 loads); drain T0
  STAGE_ALL(0, 0);
  STAGE_ALL(1, 1);
  VMCNT(8);   // 16 outstanding -> oldest 8 (all of T0) drained
  BAR();

  for (int t = 0; t < NT; t += 2) {
    TILE(0, t);
    TILE(1, t + 1);
  }

  // epilogue
  const int ncol = lane & 15;
  const int qrow = (lane >> 4) * 4;
  float bv[4];
#pragma unroll
  for (int ni = 0; ni < 4; ++ni)
    bv[ni] = bias[bn * BN + wn * 64 + ni * 16 + ncol];
#pragma unroll
  for (int mi = 0; mi < 8; ++mi)
#pragma unroll
    for (int ni = 0; ni < 4; ++ni) {
      const int gn = bn * BN + wn * 64 + ni * 16 + ncol;
#pragma unroll
      for (int r = 0; r < 4; ++r) {
        const int gm = bm * BM + wm * 128 + mi * 16 + qrow + r;
        C[(size_t)gm * OUTF + gn] = acc[mi][ni][r] + bv[ni];
      }
    }
}

// ---------------- fused fallback (no workspace requirement) ----------------

#define FBM 128
#define FBN 128

#define FMFMA_COMPUTE()                                                       \
  do {                                                                        \
    const int frr = lane & 15;                                                \
    const int fq4 = lane >> 4;                                                \
    _Pragma("unroll") for (int ks = 0; ks < 2; ++ks) {                        \
      bf16x8 fa[4], fb[4];                                                    \
      const int kk = (((ks * 4 + fq4) ^ (frr & 7)) * 8);                      \
      _Pragma("unroll") for (int i = 0; i < 4; ++i) {                         \
        fa[i] = *(const bf16x8*)&Asf[(mwave + i * 16 + frr) * BK + kk];       \
        fb[i] = *(const bf16x8*)&Bsf[(nwave + i * 16 + frr) * BK + kk];       \
      }                                                                       \
      _Pragma("unroll") for (int mi = 0; mi < 4; ++mi)                        \
        _Pragma("unroll") for (int ni = 0; ni < 4; ++ni)                      \
          facc[mi][ni] = __builtin_amdgcn_mfma_f32_16x16x32_bf16(             \
              fa[mi], fb[ni], facc[mi][ni], 0, 0, 0);                         \
    }                                                                         \
  } while (0)

__global__ __launch_bounds__(256) void gemm_fused(const float* __restrict__ X,
                                                  const int* __restrict__ QW,
                                                  const float* __restrict__ scales,
                                                  const float* __restrict__ zeros,
                                                  const float* __restrict__ bias,
                                                  float* __restrict__ C) {
  __shared__ __align__(16) u16 Asf[FBM * BK];
  __shared__ __align__(16) u16 Bsf[FBN * BK];
  const int tid = threadIdx.x;
  const int lane = tid & 63;
  const int wid = tid >> 6;
  const int bm = blockIdx.y, bn = blockIdx.x;
  const int row = tid >> 1;
  const int half = tid & 1;
  const float* xr = X + (size_t)(bm * FBM + row) * INF + half * 32;
  const int* qr = QW + (size_t)(bn * FBN + row) * KB4 + half * 16;
  const float* srow = scales + (size_t)(bn * FBN + row) * NG;
  const float* zrow = zeros + (size_t)(bn * FBN + row) * NG;
  const int mwave = (wid >> 1) * 64;
  const int nwave = (wid & 1) * 64;
  f32x4 facc[4][4] = {};

  for (int kb = 0; kb < INF / BK; ++kb) {
    const int k0 = kb * BK;
    union { u16 t[32]; int4 v[4]; } ta, tb;
#pragma unroll
    for (int j = 0; j < 8; ++j) {
      const float4 f = *(const float4*)(xr + k0 + j * 4);
      ta.t[4 * j]     = f2bf(f.x);
      ta.t[4 * j + 1] = f2bf(f.y);
      ta.t[4 * j + 2] = f2bf(f.z);
      ta.t[4 * j + 3] = f2bf(f.w);
    }
    {
      const float s = srow[kb >> 1];
      const float zs = -zrow[kb >> 1] * s;
#pragma unroll
      for (int j = 0; j < 4; ++j) {
        const int4 q = *(const int4*)(qr + kb * 32 + j * 4);
        const int qq[4] = {q.x, q.y, q.z, q.w};
#pragma unroll
        for (int u = 0; u < 4; ++u) {
          tb.t[8 * j + 2 * u]     = f2bf(fmaf((float)(qq[u] & 15), s, zs));
          tb.t[8 * j + 2 * u + 1] = f2bf(fmaf((float)((qq[u] >> 4) & 15), s, zs));
        }
      }
    }
    __syncthreads();
#pragma unroll
    for (int j = 0; j < 4; ++j) {
      *(int4*)&Asf[row * BK + (((half * 4 + j) ^ (row & 7)) * 8)] = ta.v[j];
      *(int4*)&Bsf[row * BK + (((half * 4 + j) ^ (row & 7)) * 8)] = tb.v[j];
    }
    __syncthreads();
    FMFMA_COMPUTE();
  }
  {
    const int ncol = lane & 15;
    const int qrow = (lane >> 4) * 4;
#pragma unroll
    for (int mi = 0; mi < 4; ++mi)
#pragma unroll
      for (int ni = 0; ni < 4; ++ni) {
        const int gn = bn * FBN + nwave + ni * 16 + ncol;
        const float bvv = bias[gn];
#pragma unroll
        for (int r = 0; r < 4; ++r) {
          const int gm = bm * FBM + mwave + mi * 16 + qrow + r;
          C[(size_t)gm * OUTF + gn] = facc[mi][ni][r] + bvv;
        }
      }
  }
}

// ---------------- launch ----------------

extern "C" void kernel_launch(void* const* d_in, const int* in_sizes, int n_in,
                              void* d_out, int out_size, void* d_ws, size_t ws_size,
                              hipStream_t stream) {
  const float* x = (const float*)d_in[0];
  const int* qw = (const int*)d_in[1];
  const float* scales = (const float*)d_in[2];
  const float* zeros = (const float*)d_in[3];
  const float* bias = (const float*)d_in[4];
  float* out = (float*)d_out;

  const size_t needW = (size_t)OUTF * INF * sizeof(u16);  // 90,177,536 B
  const size_t needX = (size_t)TOK * INF * sizeof(u16);   // 67,108,864 B

  if (ws_size >= needW + needX) {
    u16* Wb = (u16*)d_ws;
    u16* Xb = (u16*)((char*)d_ws + needW);
    prep<<<PREPBLK, 256, 0, stream>>>(x, qw, scales, zeros, Xb, Wb);
    gemm_pre512<<<dim3(NWG), 512, 0, stream>>>(Xb, Wb, bias, out);
  } else {
    gemm_fused<<<dim3(OUTF / FBN, TOK / FBM), 256, 0, stream>>>(x, qw, scales, zeros, bias, out);
  }
}

// Round 4
// 1265.353 us; speedup vs baseline: 1.0304x; 1.0076x over previous
//
#include <hip/hip_runtime.h>
#include <stdint.h>

#define OUTF 11008
#define INF  4096
#define NG   32      // groups = INF/128
#define TOK  8192
#define KB4  2048    // int32 per qweight row = INF/2

// ---- main GEMM geometry: 256x256 tile, 8 waves, quadrant-pipelined ----
#define BM 256
#define BN 256
#define BK 64
#define NT (INF / BK)    // 64 K-tiles
#define GX (OUTF / BN)   // 43
#define GY (TOK / BM)    // 32
#define NWG (GX * GY)    // 1376, % 8 == 0 -> simple bijective XCD swizzle

typedef unsigned short u16;
typedef __attribute__((ext_vector_type(8))) short bf16x8;
typedef __attribute__((ext_vector_type(4))) float f32x4;

// fp32 -> bf16 round-to-nearest-even (inputs finite)
__device__ inline u16 f2bf(float f) {
  union { float f; uint32_t u; } v; v.f = f;
  return (u16)((v.u + 0x7fff + ((v.u >> 16) & 1)) >> 16);
}

// async global->LDS, 16B per lane; lds dest must be wave-uniform base (+lane*16 implicit)
__device__ inline void async_copy16(const void* g, const void* l) {
  __builtin_amdgcn_global_load_lds(
      (__attribute__((address_space(1))) void*)(g),
      (__attribute__((address_space(3))) void*)(l), 16, 0, 0);
}

#define FENCE() asm volatile("" ::: "memory")
#define BAR()   do { FENCE(); __builtin_amdgcn_s_barrier(); FENCE(); } while (0)
#define VMCNT(n) asm volatile("s_waitcnt vmcnt(" #n ")" ::: "memory")
#define LGKM0()  asm volatile("s_waitcnt lgkmcnt(0)" ::: "memory")

// ---------------- fused preprocessing kernel (unchanged from round 3) ----------------

#define NXU ((long long)TOK * INF / 4)    // 8,388,608
#define NWU ((long long)OUTF * KB4 / 4)   // 5,636,096
#define PREPBLK 2048

__global__ __launch_bounds__(256) void prep(const float* __restrict__ X,
                                            const int* __restrict__ QW,
                                            const float* __restrict__ scales,
                                            const float* __restrict__ zeros,
                                            u16* __restrict__ Xb,
                                            u16* __restrict__ Wb) {
  const long long stride = (long long)gridDim.x * 256;
  for (long long i = (long long)blockIdx.x * 256 + threadIdx.x; i < NXU + NWU;
       i += stride) {
    if (i < NXU) {
      const float4 f = ((const float4*)X)[i];
      union { u16 t[4]; uint2 v; } u;
      u.t[0] = f2bf(f.x); u.t[1] = f2bf(f.y);
      u.t[2] = f2bf(f.z); u.t[3] = f2bf(f.w);
      ((uint2*)Xb)[i] = u.v;
    } else {
      const long long j = i - NXU;          // w-unit: 4 ints of row o
      const int o = (int)(j >> 9);          // 512 units per row (2048/4)
      const int c0 = ((int)j & 511) * 4;    // int column; group = c0/64 (4 | 64)
      const int g = c0 >> 6;
      const float s = scales[o * NG + g];
      const float zs = -zeros[o * NG + g] * s;
      const int4 q = ((const int4*)QW)[j];
      const int qq[4] = {q.x, q.y, q.z, q.w};
      union { u16 t[8]; int4 v; } u;
#pragma unroll
      for (int k = 0; k < 4; ++k) {
        u.t[2 * k]     = f2bf(fmaf((float)(qq[k] & 15), s, zs));
        u.t[2 * k + 1] = f2bf(fmaf((float)((qq[k] >> 4) & 15), s, zs));
      }
      ((int4*)Wb)[j] = u.v;                 // bf16 cols [2*c0, 2*c0+8)
    }
  }
}

// ---------------- main GEMM: quadrant-pipelined, 1 barrier/K-tile ----------------
// LDS XOR-swizzle: 16B granule g of local row r at g ^ (r&7), via pre-swizzled
// GLOBAL source granule + linear LDS dest. Verified conflict-free (physical
// granule = (ks*4+q4)^(rr&7): each 16-lane group covers 8 bank-groups 2-way).
// A-frag: A[m=lane&15][k=(lane>>4)*8+j]; C/D: col=lane&15, row=(lane>>4)*4+reg.
//
// Per K-tile T (slot S=T&1, other O=S^1), quadrant windows; each window has
// the NEXT window's ds_reads in flight alongside its 16 MFMAs (spread 4/8/8/4):
//   Q0 (mq0 x nq0: aLo x BX)  || read BYv <- B.nq1(T)   [slot S]
//   Q1 (mq0 x nq1: aLo x BYv) || read aHi <- A.mq1(T)   [slot S]
//   LGKM0 (drain ~300cyc-old reads: s_barrier does NOT drain lgkm, and the
//          DMA staging below would race pending reads); VMCNT(0) (drains
//          T+1's staging, issued ~1.25 tiles ago -> effectively free); BAR.
//   stage T+2 -> slot S (its last reader, Q1's aHi read, certified by BAR)
//   Q2 (mq1 x nq1: aHi x BYv) || read aLo <- A.mq0(T+1) [slot O, visible]
//   Q3 (mq1 x nq0: aHi x BX)  || read BYv <- B.nq0(T+1) [slot O; BYv dead
//                                after Q2, so next tile's BX := this BYv]
// No barrier at the tile boundary: Q0(T+1) consumes regs only, and all its
// reads target slot O which was certified at this tile's mid-barrier.
// B-buffers alternate roles per tile: TILE(0,t,bP,bQ); TILE(1,t+1,bQ,bP).

__global__ __launch_bounds__(512, 2) void gemm_pre512(const u16* __restrict__ A,
                                                      const u16* __restrict__ B,
                                                      const float* __restrict__ bias,
                                                      float* __restrict__ C) {
  __shared__ __align__(16) u16 As[2][BM * BK];   // 2 x 32 KB
  __shared__ __align__(16) u16 Bs[2][BN * BK];   // 2 x 32 KB  (total 128 KB)
  const int tid = threadIdx.x;
  const int lane = tid & 63;
  const int wid = __builtin_amdgcn_readfirstlane(tid >> 6);

  // XCD-aware bijective block swizzle (NWG % 8 == 0)
  const int lin = blockIdx.x;
  const int wg = (lin & 7) * (NWG / 8) + (lin >> 3);
  const int bm = wg / GX;
  const int bn = wg % GX;

  const u16* Ab = A + (size_t)bm * BM * INF;
  const u16* Bb = B + (size_t)bn * BN * INF;

  // staging addressing: one global_load_lds (all 8 waves) covers 64 rows
  const int rowoff = tid >> 3;                    // 0..63
  const int gran = (tid & 7) ^ (rowoff & 7);      // pre-swizzled source granule
  const u16* Asrc = Ab + (size_t)rowoff * INF + gran * 8;
  const u16* Bsrc = Bb + (size_t)rowoff * INF + gran * 8;
  const int wid8 = wid * 8;

  // frag addressing
  const int rr = lane & 15;
  const int q4 = lane >> 4;
  const int wm = wid >> 2;   // 0..1 -> 128-row half of A tile
  const int wn = wid & 3;    // 0..3 -> 64-row quarter of B tile

  f32x4 acc[8][4] = {};
  bf16x8 aLo[4][2], aHi[4][2];   // A.mq0 / A.mq1 frags (4 mi x 2 ks each)
  bf16x8 bP[2][2], bQ[2][2];     // B quadrant buffers (2 ni x 2 ks each)

// single 64-row staging call (1 VMEM instr/wave; wave w covers rows R0+8w..+7)
#define STAGE1(LDS, SRC, TT, R0)                                               \
  async_copy16((SRC) + (size_t)(R0) * INF + (size_t)(TT) * BK,                 \
               (const char*)(LDS) + ((R0) + wid8) * 128);

#define STAGE_ALL(S, TT)                                                       \
  do {                                                                         \
    STAGE1(&As[S][0], Asrc, TT, 0)   STAGE1(&As[S][0], Asrc, TT, 64)           \
    STAGE1(&As[S][0], Asrc, TT, 128) STAGE1(&As[S][0], Asrc, TT, 192)          \
    STAGE1(&Bs[S][0], Bsrc, TT, 0)   STAGE1(&Bs[S][0], Bsrc, TT, 64)           \
    STAGE1(&Bs[S][0], Bsrc, TT, 128) STAGE1(&Bs[S][0], Bsrc, TT, 192)          \
  } while (0)

// 8 ds_read_b128: one A-quadrant (64 rows, both ks)
#define RD_A(DST, S, MH)                                                       \
  _Pragma("unroll") for (int mi = 0; mi < 4; ++mi)                             \
    _Pragma("unroll") for (int ks = 0; ks < 2; ++ks)                           \
      DST[mi][ks] = *(const bf16x8*)&As[S][                                    \
          (wm * 128 + (MH) * 64 + mi * 16 + rr) * BK +                         \
          (((ks * 4 + q4) ^ (rr & 7)) * 8)];

// 4 ds_read_b128: one B-quadrant (32 cols, both ks)
#define RD_B(DST, S, NH)                                                       \
  _Pragma("unroll") for (int ni = 0; ni < 2; ++ni)                             \
    _Pragma("unroll") for (int ks = 0; ks < 2; ++ks)                           \
      DST[ni][ks] = *(const bf16x8*)&Bs[S][                                    \
          (wn * 64 + (NH) * 32 + ni * 16 + rr) * BK +                         \
          (((ks * 4 + q4) ^ (rr & 7)) * 8)];

// 16 MFMA: one C-quadrant over K=64
#define MFMAQ(AQ, BQm, MH, NH)                                                 \
  do {                                                                         \
    __builtin_amdgcn_s_setprio(1);                                             \
    _Pragma("unroll") for (int ks = 0; ks < 2; ++ks)                           \
      _Pragma("unroll") for (int mi = 0; mi < 4; ++mi)                         \
        _Pragma("unroll") for (int ni = 0; ni < 2; ++ni)                       \
          acc[(MH) * 4 + mi][(NH) * 2 + ni] =                                  \
              __builtin_amdgcn_mfma_f32_16x16x32_bf16(                         \
                  AQ[mi][ks], BQm[ni][ks],                                     \
                  acc[(MH) * 4 + mi][(NH) * 2 + ni], 0, 0, 0);                 \
    __builtin_amdgcn_s_setprio(0);                                             \
  } while (0)

#define TILE(S, T, BX, BYv)                                                    \
  do {                                                                         \
    RD_B(BYv, S, 1);                 /* Q0 window: prefetch B.nq1(T) */        \
    MFMAQ(aLo, BX, 0, 0);                                                      \
    RD_A(aHi, S, 1);                 /* Q1 window: prefetch A.mq1(T) */        \
    MFMAQ(aLo, BYv, 0, 1);                                                     \
    LGKM0(); VMCNT(0); BAR();        /* mid-tile sync (see header comment) */  \
    if ((T) + 2 < NT) STAGE_ALL(S, (T) + 2);                                   \
    if ((T) + 1 < NT) RD_A(aLo, (S) ^ 1, 0); /* Q2: prefetch A.mq0(T+1) */     \
    MFMAQ(aHi, BYv, 1, 1);                                                     \
    if ((T) + 1 < NT) RD_B(BYv, (S) ^ 1, 0); /* Q3: prefetch B.nq0(T+1) */     \
    MFMAQ(aHi, BX, 1, 0);                                                      \
  } while (0)

  // prologue: stage T0 -> slot0, T1 -> slot1; drain T0 (oldest 8 of 16); then
  // pre-read tile 0's Q0 frags so the steady-state pipeline enters primed.
  STAGE_ALL(0, 0);
  STAGE_ALL(1, 1);
  VMCNT(8);
  BAR();
  RD_A(aLo, 0, 0);
  RD_B(bP, 0, 0);

  for (int t = 0; t < NT; t += 2) {
    TILE(0, t, bP, bQ);
    TILE(1, t + 1, bQ, bP);
  }

  // epilogue
  const int ncol = lane & 15;
  const int qrow = (lane >> 4) * 4;
  float bv[4];
#pragma unroll
  for (int ni = 0; ni < 4; ++ni)
    bv[ni] = bias[bn * BN + wn * 64 + ni * 16 + ncol];
#pragma unroll
  for (int mi = 0; mi < 8; ++mi)
#pragma unroll
    for (int ni = 0; ni < 4; ++ni) {
      const int gn = bn * BN + wn * 64 + ni * 16 + ncol;
#pragma unroll
      for (int r = 0; r < 4; ++r) {
        const int gm = bm * BM + wm * 128 + mi * 16 + qrow + r;
        C[(size_t)gm * OUTF + gn] = acc[mi][ni][r] + bv[ni];
      }
    }
}

// ---------------- fused fallback (no workspace requirement) ----------------

#define FBM 128
#define FBN 128

#define FMFMA_COMPUTE()                                                       \
  do {                                                                        \
    const int frr = lane & 15;                                                \
    const int fq4 = lane >> 4;                                                \
    _Pragma("unroll") for (int ks = 0; ks < 2; ++ks) {                        \
      bf16x8 fa[4], fb[4];                                                    \
      const int kk = (((ks * 4 + fq4) ^ (frr & 7)) * 8);                      \
      _Pragma("unroll") for (int i = 0; i < 4; ++i) {                         \
        fa[i] = *(const bf16x8*)&Asf[(mwave + i * 16 + frr) * BK + kk];       \
        fb[i] = *(const bf16x8*)&Bsf[(nwave + i * 16 + frr) * BK + kk];       \
      }                                                                       \
      _Pragma("unroll") for (int mi = 0; mi < 4; ++mi)                        \
        _Pragma("unroll") for (int ni = 0; ni < 4; ++ni)                      \
          facc[mi][ni] = __builtin_amdgcn_mfma_f32_16x16x32_bf16(             \
              fa[mi], fb[ni], facc[mi][ni], 0, 0, 0);                         \
    }                                                                         \
  } while (0)

__global__ __launch_bounds__(256) void gemm_fused(const float* __restrict__ X,
                                                  const int* __restrict__ QW,
                                                  const float* __restrict__ scales,
                                                  const float* __restrict__ zeros,
                                                  const float* __restrict__ bias,
                                                  float* __restrict__ C) {
  __shared__ __align__(16) u16 Asf[FBM * BK];
  __shared__ __align__(16) u16 Bsf[FBN * BK];
  const int tid = threadIdx.x;
  const int lane = tid & 63;
  const int wid = tid >> 6;
  const int bm = blockIdx.y, bn = blockIdx.x;
  const int row = tid >> 1;
  const int half = tid & 1;
  const float* xr = X + (size_t)(bm * FBM + row) * INF + half * 32;
  const int* qr = QW + (size_t)(bn * FBN + row) * KB4 + half * 16;
  const float* srow = scales + (size_t)(bn * FBN + row) * NG;
  const float* zrow = zeros + (size_t)(bn * FBN + row) * NG;
  const int mwave = (wid >> 1) * 64;
  const int nwave = (wid & 1) * 64;
  f32x4 facc[4][4] = {};

  for (int kb = 0; kb < INF / BK; ++kb) {
    const int k0 = kb * BK;
    union { u16 t[32]; int4 v[4]; } ta, tb;
#pragma unroll
    for (int j = 0; j < 8; ++j) {
      const float4 f = *(const float4*)(xr + k0 + j * 4);
      ta.t[4 * j]     = f2bf(f.x);
      ta.t[4 * j + 1] = f2bf(f.y);
      ta.t[4 * j + 2] = f2bf(f.z);
      ta.t[4 * j + 3] = f2bf(f.w);
    }
    {
      const float s = srow[kb >> 1];
      const float zs = -zrow[kb >> 1] * s;
#pragma unroll
      for (int j = 0; j < 4; ++j) {
        const int4 q = *(const int4*)(qr + kb * 32 + j * 4);
        const int qq[4] = {q.x, q.y, q.z, q.w};
#pragma unroll
        for (int u = 0; u < 4; ++u) {
          tb.t[8 * j + 2 * u]     = f2bf(fmaf((float)(qq[u] & 15), s, zs));
          tb.t[8 * j + 2 * u + 1] = f2bf(fmaf((float)((qq[u] >> 4) & 15), s, zs));
        }
      }
    }
    __syncthreads();
#pragma unroll
    for (int j = 0; j < 4; ++j) {
      *(int4*)&Asf[row * BK + (((half * 4 + j) ^ (row & 7)) * 8)] = ta.v[j];
      *(int4*)&Bsf[row * BK + (((half * 4 + j) ^ (row & 7)) * 8)] = tb.v[j];
    }
    __syncthreads();
    FMFMA_COMPUTE();
  }
  {
    const int ncol = lane & 15;
    const int qrow = (lane >> 4) * 4;
#pragma unroll
    for (int mi = 0; mi < 4; ++mi)
#pragma unroll
      for (int ni = 0; ni < 4; ++ni) {
        const int gn = bn * FBN + nwave + ni * 16 + ncol;
        const float bvv = bias[gn];
#pragma unroll
        for (int r = 0; r < 4; ++r) {
          const int gm = bm * FBM + mwave + mi * 16 + qrow + r;
          C[(size_t)gm * OUTF + gn] = facc[mi][ni][r] + bvv;
        }
      }
  }
}

// ---------------- launch ----------------

extern "C" void kernel_launch(void* const* d_in, const int* in_sizes, int n_in,
                              void* d_out, int out_size, void* d_ws, size_t ws_size,
                              hipStream_t stream) {
  const float* x = (const float*)d_in[0];
  const int* qw = (const int*)d_in[1];
  const float* scales = (const float*)d_in[2];
  const float* zeros = (const float*)d_in[3];
  const float* bias = (const float*)d_in[4];
  float* out = (float*)d_out;

  const size_t needW = (size_t)OUTF * INF * sizeof(u16);  // 90,177,536 B
  const size_t needX = (size_t)TOK * INF * sizeof(u16);   // 67,108,864 B

  if (ws_size >= needW + needX) {
    u16* Wb = (u16*)d_ws;
    u16* Xb = (u16*)((char*)d_ws + needW);
    prep<<<PREPBLK, 256, 0, stream>>>(x, qw, scales, zeros, Xb, Wb);
    gemm_pre512<<<dim3(NWG), 512, 0, stream>>>(Xb, Wb, bias, out);
  } else {
    gemm_fused<<<dim3(OUTF / FBN, TOK / FBM), 256, 0, stream>>>(x, qw, scales, zeros, bias, out);
  }
}